// Round 1
// baseline (1593.444 us; speedup 1.0000x reference)
//
#include <hip/hip_runtime.h>
#include <math.h>

#define H_HEADS 8
#define C_DIM 32
#define HC_DIM 256
#define E_DIM 32

static __device__ __forceinline__ const float4& ldf4(const float* p) {
    return *reinterpret_cast<const float4*>(p);
}

// ---------------- CSR build ----------------
__global__ __launch_bounds__(256) void count_kernel(const int* __restrict__ dst, int E,
                                                    int* __restrict__ cnt) {
    int e = blockIdx.x * 256 + threadIdx.x;
    if (e < E) atomicAdd(&cnt[dst[e]], 1);
}

__global__ __launch_bounds__(1024) void scan_kernel(int* __restrict__ cnt,
                                                    int* __restrict__ rowptr, int n) {
    __shared__ int sm[1024];
    __shared__ int carry;
    if (threadIdx.x == 0) carry = 0;
    __syncthreads();
    for (int base = 0; base < n; base += 1024) {
        int i = base + (int)threadIdx.x;
        int val = (i < n) ? cnt[i] : 0;
        sm[threadIdx.x] = val;
        __syncthreads();
        for (int off = 1; off < 1024; off <<= 1) {
            int t = (threadIdx.x >= (unsigned)off) ? sm[threadIdx.x - off] : 0;
            __syncthreads();
            sm[threadIdx.x] += t;
            __syncthreads();
        }
        int incl = sm[threadIdx.x];
        int excl = carry + incl - val;
        if (i < n) { rowptr[i] = excl; cnt[i] = excl; }
        __syncthreads();
        if (threadIdx.x == 1023) carry += sm[1023];
        __syncthreads();
    }
    if (threadIdx.x == 0) rowptr[n] = carry;
}

__global__ __launch_bounds__(256) void scatter_kernel(const int* __restrict__ dst, int E,
                                                      int* __restrict__ cursor,
                                                      int* __restrict__ elist) {
    int e = blockIdx.x * 256 + threadIdx.x;
    if (e < E) {
        int p = atomicAdd(&cursor[dst[e]], 1);
        elist[p] = e;
    }
}

// ---------------- f32 GEMM: Y[M,N] = A[M,K] @ W[K,N] + bias[N] ----------------
__global__ __launch_bounds__(256) void gemm_bias(const float* __restrict__ A,
                                                 const float* __restrict__ W,
                                                 const float* __restrict__ bias,
                                                 float* __restrict__ Y,
                                                 int M, int N, int K) {
    __shared__ float As[16][68];
    __shared__ float Ws[16][68];
    const int tid = threadIdx.x;
    const int tx = tid & 15, ty = tid >> 4;
    const int m0 = blockIdx.x * 64, n0 = blockIdx.y * 64;
    const int lm = tid >> 2;           // A row within tile (0..63)
    const int lk = (tid & 3) << 2;     // A k within tile (0,4,8,12)
    const int wk = tid >> 4;           // W k row within tile (0..15)
    const int wn = (tid & 15) << 2;    // W col within tile (0..60)
    float acc[4][4] = {{0.f}};
    for (int k0 = 0; k0 < K; k0 += 16) {
        float4 a = {0.f, 0.f, 0.f, 0.f};
        if (m0 + lm < M) a = ldf4(A + (size_t)(m0 + lm) * K + k0 + lk);
        As[lk + 0][lm] = a.x; As[lk + 1][lm] = a.y;
        As[lk + 2][lm] = a.z; As[lk + 3][lm] = a.w;
        float4 w = {0.f, 0.f, 0.f, 0.f};
        if (n0 + wn < N) w = ldf4(W + (size_t)(k0 + wk) * N + n0 + wn);
        *reinterpret_cast<float4*>(&Ws[wk][wn]) = w;
        __syncthreads();
#pragma unroll
        for (int kk = 0; kk < 16; ++kk) {
            float4 av = *reinterpret_cast<const float4*>(&As[kk][ty << 2]);
            float4 bv = *reinterpret_cast<const float4*>(&Ws[kk][tx << 2]);
            float aa[4] = {av.x, av.y, av.z, av.w};
            float bb[4] = {bv.x, bv.y, bv.z, bv.w};
#pragma unroll
            for (int i = 0; i < 4; ++i)
#pragma unroll
                for (int j = 0; j < 4; ++j)
                    acc[i][j] = fmaf(aa[i], bb[j], acc[i][j]);
        }
        __syncthreads();
    }
    if (n0 + (tx << 2) < N) {
        float4 bb = ldf4(bias + n0 + (tx << 2));
#pragma unroll
        for (int i = 0; i < 4; ++i) {
            int m = m0 + (ty << 2) + i;
            if (m < M) {
                float4 o;
                o.x = acc[i][0] + bb.x; o.y = acc[i][1] + bb.y;
                o.z = acc[i][2] + bb.z; o.w = acc[i][3] + bb.w;
                *reinterpret_cast<float4*>(Y + (size_t)m * N + n0 + (tx << 2)) = o;
            }
        }
    }
}

// ---------------- conv1 attention: one wave per dst node ----------------
// lane holds hc = 4*lane .. 4*lane+3 ; head = lane>>3
__global__ __launch_bounds__(256) void attn1_kernel(
    const float* __restrict__ q, const float* __restrict__ k,
    const float* __restrict__ v, const float* __restrict__ skip,
    const float* __restrict__ edge_attr, const float* __restrict__ we,
    const int* __restrict__ src, const int* __restrict__ rowptr,
    const int* __restrict__ elist, const float* __restrict__ gamma,
    const float* __restrict__ beta, float* __restrict__ hout, int nN) {
    const int wid = threadIdx.x >> 6, lane = threadIdx.x & 63;
    const int node = blockIdx.x * 4 + wid;
    if (node >= nN) return;
    const int hc0 = lane << 2;
    float4 wreg[E_DIM];
#pragma unroll
    for (int d = 0; d < E_DIM; ++d) wreg[d] = ldf4(we + d * HC_DIM + hc0);
    const float4 qv = ldf4(q + (size_t)node * HC_DIM + hc0);
    float m = -INFINITY, denom = 0.f;
    float ax = 0.f, ay = 0.f, az = 0.f, aw = 0.f;
    const int e0 = rowptr[node], e1 = rowptr[node + 1];
    for (int ei = e0; ei < e1; ++ei) {
        const int e = elist[ei];
        const int s = src[e];
        const float* ea = edge_attr + (size_t)e * E_DIM;
        float efx = 0.f, efy = 0.f, efz = 0.f, efw = 0.f;
#pragma unroll
        for (int d4 = 0; d4 < E_DIM / 4; ++d4) {
            float4 t = ldf4(ea + d4 * 4);
            float ts[4] = {t.x, t.y, t.z, t.w};
#pragma unroll
            for (int j = 0; j < 4; ++j) {
                float4 wv = wreg[d4 * 4 + j];
                efx = fmaf(ts[j], wv.x, efx);
                efy = fmaf(ts[j], wv.y, efy);
                efz = fmaf(ts[j], wv.z, efz);
                efw = fmaf(ts[j], wv.w, efw);
            }
        }
        const float4 kv = ldf4(k + (size_t)s * HC_DIM + hc0);
        float lp = qv.x * (kv.x + efx) + qv.y * (kv.y + efy) +
                   qv.z * (kv.z + efz) + qv.w * (kv.w + efw);
        lp += __shfl_xor(lp, 1); lp += __shfl_xor(lp, 2); lp += __shfl_xor(lp, 4);
        const float l = lp * 0.17677669529663687f;  // 1/sqrt(32)
        const float mn = fmaxf(m, l);
        const float sc = __expf(m - mn);
        const float w = __expf(l - mn);
        const float4 vv = ldf4(v + (size_t)s * HC_DIM + hc0);
        denom = denom * sc + w;
        ax = ax * sc + w * (vv.x + efx);
        ay = ay * sc + w * (vv.y + efy);
        az = az * sc + w * (vv.z + efz);
        aw = aw * sc + w * (vv.w + efw);
        m = mn;
    }
    const float inv = 1.f / (denom + 1e-16f);
    const float4 sk = ldf4(skip + (size_t)node * HC_DIM + hc0);
    float ox = fmaxf(ax * inv + sk.x, 0.f);
    float oy = fmaxf(ay * inv + sk.y, 0.f);
    float oz = fmaxf(az * inv + sk.z, 0.f);
    float ow = fmaxf(aw * inv + sk.w, 0.f);
    float s1 = ox + oy + oz + ow;
    float s2 = ox * ox + oy * oy + oz * oz + ow * ow;
#pragma unroll
    for (int msk = 1; msk < 64; msk <<= 1) {
        s1 += __shfl_xor(s1, msk);
        s2 += __shfl_xor(s2, msk);
    }
    const float mu = s1 * (1.f / 256.f);
    const float var = s2 * (1.f / 256.f) - mu * mu;
    const float rstd = rsqrtf(var + 1e-5f);
    const float4 gv = ldf4(gamma + hc0);
    const float4 bv = ldf4(beta + hc0);
    float4 o;
    o.x = (ox - mu) * rstd * gv.x + bv.x;
    o.y = (oy - mu) * rstd * gv.y + bv.y;
    o.z = (oz - mu) * rstd * gv.z + bv.z;
    o.w = (ow - mu) * rstd * gv.w + bv.w;
    *reinterpret_cast<float4*>(hout + (size_t)node * HC_DIM + hc0) = o;
}

// ---------------- conv2 attention + head-mean + skip + relu + final linear ----------------
__global__ __launch_bounds__(256) void attn2_kernel(
    const float* __restrict__ q, const float* __restrict__ k,
    const float* __restrict__ v, const float* __restrict__ skip2,  // [N,32] incl bias
    const float* __restrict__ edge_attr, const float* __restrict__ we,
    const int* __restrict__ src, const int* __restrict__ rowptr,
    const int* __restrict__ elist, const float* __restrict__ wc,  // [32,2]
    const float* __restrict__ bc, float* __restrict__ out, int nN) {
    const int wid = threadIdx.x >> 6, lane = threadIdx.x & 63;
    const int node = blockIdx.x * 4 + wid;
    if (node >= nN) return;
    const int hc0 = lane << 2;
    float4 wreg[E_DIM];
#pragma unroll
    for (int d = 0; d < E_DIM; ++d) wreg[d] = ldf4(we + d * HC_DIM + hc0);
    const float4 qv = ldf4(q + (size_t)node * HC_DIM + hc0);
    float m = -INFINITY, denom = 0.f;
    float ax = 0.f, ay = 0.f, az = 0.f, aw = 0.f;
    const int e0 = rowptr[node], e1 = rowptr[node + 1];
    for (int ei = e0; ei < e1; ++ei) {
        const int e = elist[ei];
        const int s = src[e];
        const float* ea = edge_attr + (size_t)e * E_DIM;
        float efx = 0.f, efy = 0.f, efz = 0.f, efw = 0.f;
#pragma unroll
        for (int d4 = 0; d4 < E_DIM / 4; ++d4) {
            float4 t = ldf4(ea + d4 * 4);
            float ts[4] = {t.x, t.y, t.z, t.w};
#pragma unroll
            for (int j = 0; j < 4; ++j) {
                float4 wv = wreg[d4 * 4 + j];
                efx = fmaf(ts[j], wv.x, efx);
                efy = fmaf(ts[j], wv.y, efy);
                efz = fmaf(ts[j], wv.z, efz);
                efw = fmaf(ts[j], wv.w, efw);
            }
        }
        const float4 kv = ldf4(k + (size_t)s * HC_DIM + hc0);
        float lp = qv.x * (kv.x + efx) + qv.y * (kv.y + efy) +
                   qv.z * (kv.z + efz) + qv.w * (kv.w + efw);
        lp += __shfl_xor(lp, 1); lp += __shfl_xor(lp, 2); lp += __shfl_xor(lp, 4);
        const float l = lp * 0.17677669529663687f;
        const float mn = fmaxf(m, l);
        const float sc = __expf(m - mn);
        const float w = __expf(l - mn);
        const float4 vv = ldf4(v + (size_t)s * HC_DIM + hc0);
        denom = denom * sc + w;
        ax = ax * sc + w * (vv.x + efx);
        ay = ay * sc + w * (vv.y + efy);
        az = az * sc + w * (vv.z + efz);
        aw = aw * sc + w * (vv.w + efw);
        m = mn;
    }
    const float inv = 1.f / (denom + 1e-16f);
    float ox = ax * inv, oy = ay * inv, oz = az * inv, ow = aw * inv;
    // mean over heads: sum lanes with equal (lane&7)
#pragma unroll
    for (int msk = 8; msk < 64; msk <<= 1) {
        ox += __shfl_xor(ox, msk);
        oy += __shfl_xor(oy, msk);
        oz += __shfl_xor(oz, msk);
        ow += __shfl_xor(ow, msk);
    }
    const int c0 = (lane & 7) << 2;
    const float4 sk = ldf4(skip2 + (size_t)node * C_DIM + c0);
    const float yx = fmaxf(ox * 0.125f + sk.x, 0.f);
    const float yy = fmaxf(oy * 0.125f + sk.y, 0.f);
    const float yz = fmaxf(oz * 0.125f + sk.z, 0.f);
    const float yw = fmaxf(ow * 0.125f + sk.w, 0.f);
    float p0 = yx * wc[(c0 + 0) * 2 + 0] + yy * wc[(c0 + 1) * 2 + 0] +
               yz * wc[(c0 + 2) * 2 + 0] + yw * wc[(c0 + 3) * 2 + 0];
    float p1 = yx * wc[(c0 + 0) * 2 + 1] + yy * wc[(c0 + 1) * 2 + 1] +
               yz * wc[(c0 + 2) * 2 + 1] + yw * wc[(c0 + 3) * 2 + 1];
#pragma unroll
    for (int msk = 1; msk < 8; msk <<= 1) {
        p0 += __shfl_xor(p0, msk);
        p1 += __shfl_xor(p1, msk);
    }
    if (lane == 0) {
        out[(size_t)node * 2 + 0] = p0 + bc[0];
        out[(size_t)node * 2 + 1] = p1 + bc[1];
    }
}

extern "C" void kernel_launch(void* const* d_in, const int* in_sizes, int n_in,
                              void* d_out, int out_size, void* d_ws, size_t ws_size,
                              hipStream_t stream) {
    const float* x        = (const float*)d_in[0];
    const int*   eidx     = (const int*)d_in[1];
    const float* eattr    = (const float*)d_in[2];
    const float* wq1      = (const float*)d_in[3];
    const float* bq1      = (const float*)d_in[4];
    const float* wk1      = (const float*)d_in[5];
    const float* bk1      = (const float*)d_in[6];
    const float* wv1      = (const float*)d_in[7];
    const float* bv1      = (const float*)d_in[8];
    const float* we1      = (const float*)d_in[9];
    const float* wskip1   = (const float*)d_in[10];
    const float* bskip1   = (const float*)d_in[11];
    const float* g1       = (const float*)d_in[12];
    const float* b1       = (const float*)d_in[13];
    const float* wq2      = (const float*)d_in[14];
    const float* bq2      = (const float*)d_in[15];
    const float* wk2      = (const float*)d_in[16];
    const float* bk2      = (const float*)d_in[17];
    const float* wv2      = (const float*)d_in[18];
    const float* bv2      = (const float*)d_in[19];
    const float* we2      = (const float*)d_in[20];
    const float* wskip2   = (const float*)d_in[21];
    const float* bskip2   = (const float*)d_in[22];
    const float* wc       = (const float*)d_in[23];
    const float* bc       = (const float*)d_in[24];

    const int N = in_sizes[0] / 128;
    const int E = in_sizes[2] / 32;
    const int* src = eidx;
    const int* dst = eidx + E;
    float* out = (float*)d_out;

    char* ws = (char*)d_ws;
    const size_t fbytes = (size_t)N * HC_DIM * sizeof(float);
    float* qb = (float*)(ws + 0 * fbytes);
    float* kb = (float*)(ws + 1 * fbytes);
    float* vb = (float*)(ws + 2 * fbytes);
    float* sb = (float*)(ws + 3 * fbytes);  // skip1 [N,256] / skip2 [N,32]
    float* hb = (float*)(ws + 4 * fbytes);
    int* rowptr = (int*)(ws + 5 * fbytes);
    int* cursor = rowptr + (N + 1);
    int* elist  = cursor + N;

    // CSR build (per-call; counts zeroed each call)
    hipMemsetAsync(cursor, 0, (size_t)N * sizeof(int), stream);
    count_kernel<<<dim3((E + 255) / 256), dim3(256), 0, stream>>>(dst, E, cursor);
    scan_kernel<<<dim3(1), dim3(1024), 0, stream>>>(cursor, rowptr, N);
    scatter_kernel<<<dim3((E + 255) / 256), dim3(256), 0, stream>>>(dst, E, cursor, elist);

    // conv1 projections
    dim3 gg((N + 63) / 64, 4);
    gemm_bias<<<gg, dim3(256), 0, stream>>>(x, wq1, bq1, qb, N, 256, 128);
    gemm_bias<<<gg, dim3(256), 0, stream>>>(x, wk1, bk1, kb, N, 256, 128);
    gemm_bias<<<gg, dim3(256), 0, stream>>>(x, wv1, bv1, vb, N, 256, 128);
    gemm_bias<<<gg, dim3(256), 0, stream>>>(x, wskip1, bskip1, sb, N, 256, 128);

    attn1_kernel<<<dim3((N + 3) / 4), dim3(256), 0, stream>>>(
        qb, kb, vb, sb, eattr, we1, src, rowptr, elist, g1, b1, hb, N);

    // conv2 projections
    gemm_bias<<<gg, dim3(256), 0, stream>>>(hb, wq2, bq2, qb, N, 256, 256);
    gemm_bias<<<gg, dim3(256), 0, stream>>>(hb, wk2, bk2, kb, N, 256, 256);
    gemm_bias<<<gg, dim3(256), 0, stream>>>(hb, wv2, bv2, vb, N, 256, 256);
    dim3 gs((N + 63) / 64, 1);
    gemm_bias<<<gs, dim3(256), 0, stream>>>(hb, wskip2, bskip2, sb, N, 32, 256);

    attn2_kernel<<<dim3((N + 3) / 4), dim3(256), 0, stream>>>(
        qb, kb, vb, sb, eattr, we2, src, rowptr, elist, wc, bc, out, N);
}